// Round 6
// baseline (257.310 us; speedup 1.0000x reference)
//
#include <hip/hip_runtime.h>

typedef __attribute__((ext_vector_type(8))) short short8;
typedef __attribute__((ext_vector_type(4))) float f32x4;
typedef __attribute__((ext_vector_type(4))) unsigned int u32x4;

#define NTOK 4096
#define DIM  256
#define P_STRIDE 72        // P row stride in elems (144 B)
#define TILE_ELEMS 32768   // ushort elems per 64KB tile image (Ks 16384 | Kt 16384)

__device__ __forceinline__ unsigned pack2bf(float a, float b) {
  unsigned ua = __builtin_bit_cast(unsigned, a) + 0x8000u;
  unsigned ub = __builtin_bit_cast(unsigned, b) + 0x8000u;
  return __builtin_amdgcn_perm(ub, ua, 0x07060302u);
}
__device__ __forceinline__ unsigned short f2bf(float f) { // RNE
  unsigned u = __builtin_bit_cast(unsigned, f);
  u += 0x7fffu + ((u >> 16) & 1u);
  return (unsigned short)(u >> 16);
}

// ---- prologue: per-tile bf16 images (unchanged layout) -------------------
// Img[b][t] = [ Ks: 64 rows x 32 chunks(16B), chunk c at (c ^ (r&7))
//             | Kt: 8 kb-blocks x 256 d x 8 tokens ]
__global__ __launch_bounds__(256, 4)
void prep_kernel(const float* __restrict__ X, unsigned short* __restrict__ Img) {
  const int b    = blockIdx.x & 3;
  const int sub  = blockIdx.x >> 2;   // 0..511
  const int t    = sub >> 3;
  const int part = sub & 7;
  const int tid  = threadIdx.x;
  const float* src = X + ((size_t)b * NTOK + t * 64) * DIM;
  unsigned short* dst = Img + ((size_t)(b * 64 + t)) * TILE_ELEMS;
  {
    int r = part * 8 + (tid >> 5);
    int c = tid & 31;
    const float* s = src + r * DIM + c * 8;
    f32x4 f0 = *(const f32x4*)s;
    f32x4 f1 = *(const f32x4*)(s + 4);
    union { unsigned u[4]; u32x4 v; } p;
    p.u[0] = pack2bf(f0[0], f0[1]);
    p.u[1] = pack2bf(f0[2], f0[3]);
    p.u[2] = pack2bf(f1[0], f1[1]);
    p.u[3] = pack2bf(f1[2], f1[3]);
    *(u32x4*)(dst + r * 256 + ((c ^ (r & 7)) << 3)) = p.v;
  }
  {
    const int d = tid;
    float f[8];
    #pragma unroll
    for (int i = 0; i < 8; ++i) f[i] = src[(part * 8 + i) * DIM + d];
    union { unsigned u[4]; u32x4 v; } p;
    p.u[0] = pack2bf(f[0], f[1]);
    p.u[1] = pack2bf(f[2], f[3]);
    p.u[2] = pack2bf(f[4], f[5]);
    p.u[3] = pack2bf(f[6], f[7]);
    *(u32x4*)(dst + 16384 + part * 2048 + d * 8) = p.v;
  }
}

// PV step for B-group waves: O[s][dt] += P[s-strip] * V[d-quarter dq]
__device__ __forceinline__ void pv_step(const unsigned short* __restrict__ Pbuf,
                                        const unsigned short* __restrict__ Ktbuf,
                                        f32x4 (&o)[4][4],
                                        int quad, int ln, int swz, int dq) {
  #pragma unroll
  for (int ks = 0; ks < 2; ++ks) {
    const int pchunk = ((ks * 4 + quad + swz) & 7) << 3;  // rotation swizzle
    short8 ap[4], bv[4];
    #pragma unroll
    for (int s = 0; s < 4; ++s)
      ap[s] = *(const short8*)(&Pbuf[(s * 16 + ln) * P_STRIDE + pchunk]);
    const unsigned short* kb = Ktbuf + (ks * 4 + quad) * 2048 + (dq * 64 + ln) * 8;
    #pragma unroll
    for (int dt = 0; dt < 4; ++dt)
      bv[dt] = *(const short8*)(kb + dt * 128);
    #pragma unroll
    for (int s = 0; s < 4; ++s)
      #pragma unroll
      for (int dt = 0; dt < 4; ++dt)
        o[s][dt] = __builtin_amdgcn_mfma_f32_16x16x32_bf16(ap[s], bv[dt], o[s][dt], 0, 0, 0);
  }
}

// ---- flash-attention: producer(QK+softmax) / consumer(PV) wave groups ----
__global__ __launch_bounds__(512, 2)
void fa_kernel(const unsigned short* __restrict__ Img, float* __restrict__ Out) {
  __shared__ __align__(16) unsigned short ksb[2][16384];     // 64 KB
  __shared__ __align__(16) unsigned short ktb[2][16384];     // 64 KB
  __shared__ __align__(16) unsigned short pb[2][64 * P_STRIDE]; // 18 KB
  __shared__ float lbuf[64][4];                              // 1 KB

  const int tid  = threadIdx.x;
  const int b    = blockIdx.x & 3;
  const int qblk = blockIdx.x >> 2;
  const int wave = tid >> 6;
  const int lane = tid & 63;
  const int ln   = lane & 15;
  const int quad = lane >> 4;
  const int swz  = ln & 7;
  const bool isA = wave < 4;
  const int role = wave & 3;   // A: key-quarter kq ; B: d-quarter dq

  const unsigned short* imgb  = Img + (size_t)b * 64 * TILE_ELEMS;
  const char*           imgbc = (const char*)imgb;

  short8 aQ[4][8];      // A-group only
  f32x4  o[4][4];       // B-group only
  float  lrow[4][4];
  const float c2 = 0.0901684400f;  // log2(e)/sqrt(256)

  if (isA) {
    const unsigned short* qt = imgb + (size_t)qblk * TILE_ELEMS;
    #pragma unroll
    for (int s = 0; s < 4; ++s) {
      const unsigned short* qrow = qt + (s * 16 + ln) * 256;
      #pragma unroll
      for (int ds = 0; ds < 8; ++ds)
        aQ[s][ds] = *(const short8*)(qrow + (((ds * 4 + quad) ^ swz) << 3));
      #pragma unroll
      for (int j = 0; j < 4; ++j) lrow[s][j] = 0.f;
    }
    // prologue DMA: Ks[0] -> ksb[0]
    const char* g = imgbc + (size_t)role * 8192 + (size_t)lane * 16;
    #pragma unroll
    for (int i = 0; i < 8; ++i)
      __builtin_amdgcn_global_load_lds(
          (const __attribute__((address_space(1))) unsigned*)(g + i * 1024),
          (__attribute__((address_space(3))) unsigned*)(&ksb[0][role * 4096 + i * 512]),
          16, 0, 0);
  } else {
    #pragma unroll
    for (int s = 0; s < 4; ++s)
      #pragma unroll
      for (int dt = 0; dt < 4; ++dt) o[s][dt] = (f32x4)(0.0f);
  }

  for (int t = 0; t < 64; ++t) {
    __syncthreads();  // drains all DMA issued last iter; tile t / P[t-1] ready
    const int buf = t & 1;

    if (isA) {
      if (t < 63) {   // DMA Ks[t+1] -> ksb[buf^1]; consumed next iter
        const char* g = imgbc + (size_t)(t + 1) * 65536 + (size_t)role * 8192 + (size_t)lane * 16;
        unsigned short* l = &ksb[buf ^ 1][role * 4096];
        #pragma unroll
        for (int i = 0; i < 8; ++i)
          __builtin_amdgcn_global_load_lds(
              (const __attribute__((address_space(1))) unsigned*)(g + i * 1024),
              (__attribute__((address_space(3))) unsigned*)(l + i * 512),
              16, 0, 0);
      }
      // QK^T: 4 strips x this wave's 16 keys, K=256
      f32x4 sf[4];
      #pragma unroll
      for (int s = 0; s < 4; ++s) sf[s] = (f32x4)(0.0f);
      const unsigned short* krow = &ksb[buf][(role * 16 + ln) * 256];
      #pragma unroll
      for (int ds = 0; ds < 8; ++ds) {
        short8 bk = *(const short8*)(krow + (((ds * 4 + quad) ^ swz) << 3));
        #pragma unroll
        for (int s = 0; s < 4; ++s)
          sf[s] = __builtin_amdgcn_mfma_f32_16x16x32_bf16(aQ[s][ds], bk, sf[s], 0, 0, 0);
      }
      // softmax numerator + P[t] (rotation chunk swizzle (kc+row)&7)
      unsigned short* pw = pb[buf];
      const int kc = role * 2 + (ln >> 3);
      #pragma unroll
      for (int s = 0; s < 4; ++s) {
        #pragma unroll
        for (int j = 0; j < 4; ++j) {
          float p = exp2f(sf[s][j] * c2);
          lrow[s][j] += p;
          const int row = s * 16 + quad * 4 + j;
          pw[row * P_STRIDE + (((kc + row) & 7) << 3) + (ln & 7)] = f2bf(p);
        }
      }
    } else {
      // DMA Kt[t] -> ktb[buf]; consumed next iter
      const char* g = imgbc + (size_t)t * 65536 + 32768 + (size_t)role * 8192 + (size_t)lane * 16;
      unsigned short* l = &ktb[buf][role * 4096];
      #pragma unroll
      for (int i = 0; i < 8; ++i)
        __builtin_amdgcn_global_load_lds(
            (const __attribute__((address_space(1))) unsigned*)(g + i * 1024),
            (__attribute__((address_space(3))) unsigned*)(l + i * 512),
            16, 0, 0);
      if (t > 0)
        pv_step(pb[buf ^ 1], ktb[buf ^ 1], o, quad, ln, swz, role);
    }
  }

  __syncthreads();  // P[63], Kt[63] ready; all tile reads done
  if (isA) {
    // reduce l over the 16 key-lanes (quad-preserving), publish per-quarter
    #pragma unroll
    for (int off = 1; off < 16; off <<= 1)
      #pragma unroll
      for (int s = 0; s < 4; ++s)
        #pragma unroll
        for (int j = 0; j < 4; ++j)
          lrow[s][j] += __shfl_xor(lrow[s][j], off, 64);
    if (ln == 0) {
      #pragma unroll
      for (int s = 0; s < 4; ++s)
        #pragma unroll
        for (int j = 0; j < 4; ++j)
          lbuf[s * 16 + quad * 4 + j][role] = lrow[s][j];
    }
  } else {
    pv_step(pb[1], ktb[1], o, quad, ln, swz, role);  // final tile 63
  }
  __syncthreads();

  if (!isA) {
    float* outp = Out + (size_t)(b * NTOK + qblk * 64) * DIM + role * 64;
    #pragma unroll
    for (int s = 0; s < 4; ++s) {
      #pragma unroll
      for (int j = 0; j < 4; ++j) {
        const int row = s * 16 + quad * 4 + j;
        f32x4 lv = *(const f32x4*)lbuf[row];
        const float rl = 1.0f / (lv[0] + lv[1] + lv[2] + lv[3]);
        #pragma unroll
        for (int dt = 0; dt < 4; ++dt)
          outp[(size_t)row * DIM + dt * 16 + ln] = o[s][dt][j] * rl;
      }
    }
  }
}

extern "C" void kernel_launch(void* const* d_in, const int* in_sizes, int n_in,
                              void* d_out, int out_size, void* d_ws, size_t ws_size,
                              hipStream_t stream) {
  const float* X = (const float*)d_in[0];       // x: fp32 [4,4096,256]
  float* Out = (float*)d_out;                   // fp32 [4,4096,256]
  unsigned short* Img = (unsigned short*)d_ws;  // 16 MB bf16 tile images
  (void)in_sizes; (void)n_in; (void)out_size; (void)ws_size;
  hipLaunchKernelGGL(prep_kernel, dim3(2048), dim3(256), 0, stream, X, Img);
  hipLaunchKernelGGL(fa_kernel, dim3(256), dim3(512), 0, stream, Img, Out);
}

// Round 7
// 173.920 us; speedup vs baseline: 1.4795x; 1.4795x over previous
//
#include <hip/hip_runtime.h>

typedef __attribute__((ext_vector_type(8))) short short8;
typedef __attribute__((ext_vector_type(4))) float f32x4;
typedef __attribute__((ext_vector_type(4))) unsigned int u32x4;

#define NTOK 4096
#define DIM  256
#define P_STRIDE 72        // P row stride elems (144 B, 16B-aligned)
#define TILE_ELEMS 32768   // ushort elems per 64KB tile image (Ks 16384 | Kt 16384)

__device__ __forceinline__ unsigned pack2bf(float a, float b) {
  unsigned ua = __builtin_bit_cast(unsigned, a) + 0x8000u;
  unsigned ub = __builtin_bit_cast(unsigned, b) + 0x8000u;
  return __builtin_amdgcn_perm(ub, ua, 0x07060302u);
}
__device__ __forceinline__ unsigned short f2bf(float f) { // RNE
  unsigned u = __builtin_bit_cast(unsigned, f);
  u += 0x7fffu + ((u >> 16) & 1u);
  return (unsigned short)(u >> 16);
}

// ---- prologue: per-tile bf16 images --------------------------------------
// Img[b][t] = [ Ks: 64 rows x 32 chunks(16B), chunk c at (c ^ (r&7))
//             | Kt: 8 kb-blocks x 256 d x 8 tokens ]
__global__ __launch_bounds__(256, 4)
void prep_kernel(const float* __restrict__ X, unsigned short* __restrict__ Img) {
  const int b    = blockIdx.x & 3;
  const int sub  = blockIdx.x >> 2;   // 0..511
  const int t    = sub >> 3;
  const int part = sub & 7;
  const int tid  = threadIdx.x;
  const float* src = X + ((size_t)b * NTOK + t * 64) * DIM;
  unsigned short* dst = Img + ((size_t)(b * 64 + t)) * TILE_ELEMS;
  {
    int r = part * 8 + (tid >> 5);
    int c = tid & 31;
    const float* s = src + r * DIM + c * 8;
    f32x4 f0 = *(const f32x4*)s;
    f32x4 f1 = *(const f32x4*)(s + 4);
    union { unsigned u[4]; u32x4 v; } p;
    p.u[0] = pack2bf(f0[0], f0[1]);
    p.u[1] = pack2bf(f0[2], f0[3]);
    p.u[2] = pack2bf(f1[0], f1[1]);
    p.u[3] = pack2bf(f1[2], f1[3]);
    *(u32x4*)(dst + r * 256 + ((c ^ (r & 7)) << 3)) = p.v;
  }
  {
    const int d = tid;
    float f[8];
    #pragma unroll
    for (int i = 0; i < 8; ++i) f[i] = src[(part * 8 + i) * DIM + d];
    union { unsigned u[4]; u32x4 v; } p;
    p.u[0] = pack2bf(f[0], f[1]);
    p.u[1] = pack2bf(f[2], f[3]);
    p.u[2] = pack2bf(f[4], f[5]);
    p.u[3] = pack2bf(f[6], f[7]);
    *(u32x4*)(dst + 16384 + part * 2048 + d * 8) = p.v;
  }
}

// ---- flash-attention: uniform waves, 1 barrier/iter, P dbuf --------------
// wave = (qh = wave&1, role = wave>>1)
// QK(t):  strips s=0,1 (rows qh*32+s*16+..), keys role*16..+15  -> P(t)
// PV(t-1): same strips, d-quarter role*64..+63, all 64 keys
__global__ __launch_bounds__(512, 1)
void fa_kernel(const unsigned short* __restrict__ Img, float* __restrict__ Out) {
  __shared__ __align__(16) unsigned short ksb[2][16384];        // 64 KB
  __shared__ __align__(16) unsigned short ktb[2][16384];        // 64 KB
  __shared__ __align__(16) unsigned short pb[2][64 * P_STRIDE]; // 18 KB
  __shared__ float lbuf[64][4];                                 // 1 KB

  const int tid  = threadIdx.x;
  const int b    = blockIdx.x & 3;
  const int qblk = blockIdx.x >> 2;
  const int wave = tid >> 6;
  const int lane = tid & 63;
  const int ln   = lane & 15;
  const int quad = lane >> 4;
  const int swz  = ln & 7;
  const int qh   = wave & 1;
  const int role = wave >> 1;

  const unsigned short* imgb  = Img + (size_t)b * 64 * TILE_ELEMS;
  const char*           imgbc = (const char*)imgb;

  // Q fragments: strips s=0,1 -> rows qh*32 + s*16 + ln
  short8 aQ[2][8];
  #pragma unroll
  for (int s = 0; s < 2; ++s) {
    const unsigned short* qrow =
        imgb + (size_t)qblk * TILE_ELEMS + (qh * 32 + s * 16 + ln) * 256;
    #pragma unroll
    for (int ds = 0; ds < 8; ++ds)
      aQ[s][ds] = *(const short8*)(qrow + (((ds * 4 + quad) ^ swz) << 3));
  }

  f32x4 o[2][4];
  #pragma unroll
  for (int s = 0; s < 2; ++s)
    #pragma unroll
    for (int dt = 0; dt < 4; ++dt) o[s][dt] = (f32x4)(0.0f);
  float lrow[2][4] = {{0.f,0.f,0.f,0.f},{0.f,0.f,0.f,0.f}};

  const float c2 = 0.0901684400f;  // log2(e)/sqrt(256)

  // P swizzle: chunk kc of row r stored at pos = (bitrev3(kc) + (r>>2)) & 7
  // write side: kc = role*2 + (ln>>3) -> bitrev3 = 4*(ln>>3) + 2*(role&1) + (role>>1)
  const int pwSig = 4 * (ln >> 3) + 2 * (role & 1) + (role >> 1);
  // read side: kc' = ks*4 + quad -> bitrev3 = 4*(quad&1) + 2*((quad>>1)&1) + ks
  const int prSigBase = 4 * (quad & 1) + 2 * ((quad >> 1) & 1);

  // DMA roles: waves 0-3 stage Ks quarters, waves 4-7 stage Kt quarters
  const bool dmaKs = wave < 4;
  const int  dmaQ  = wave & 3;
  const char* gK = imgbc + (size_t)dmaQ * 8192 + (size_t)lane * 16;          // + t*65536 [+32768 for Kt]

  // prologue: Ks(0) -> ksb[0]
  if (dmaKs) {
    #pragma unroll
    for (int i = 0; i < 8; ++i)
      __builtin_amdgcn_global_load_lds(
          (const __attribute__((address_space(1))) unsigned*)(gK + i * 1024),
          (__attribute__((address_space(3))) unsigned*)(&ksb[0][dmaQ * 4096 + i * 512]),
          16, 0, 0);
  }

  for (int t = 0; t < 64; ++t) {
    __syncthreads();  // drains last iter's DMA; P(t-1)/Ks(t)/Kt(t-1) ready
    const int buf = t & 1;

    // issue DMA early: Ks(t+1) -> ksb[buf^1], Kt(t) -> ktb[buf]
    if (dmaKs) {
      if (t < 63) {
        const char* g = gK + (size_t)(t + 1) * 65536;
        unsigned short* l = &ksb[buf ^ 1][dmaQ * 4096];
        #pragma unroll
        for (int i = 0; i < 8; ++i)
          __builtin_amdgcn_global_load_lds(
              (const __attribute__((address_space(1))) unsigned*)(g + i * 1024),
              (__attribute__((address_space(3))) unsigned*)(l + i * 512),
              16, 0, 0);
      }
    } else {
      const char* g = gK + (size_t)t * 65536 + 32768;
      unsigned short* l = &ktb[buf][dmaQ * 4096];
      #pragma unroll
      for (int i = 0; i < 8; ++i)
        __builtin_amdgcn_global_load_lds(
            (const __attribute__((address_space(1))) unsigned*)(g + i * 1024),
            (__attribute__((address_space(3))) unsigned*)(l + i * 512),
            16, 0, 0);
    }

    // --- QK(t): keys role*16..+15, both strips ---
    f32x4 sf0 = (f32x4)(0.0f), sf1 = (f32x4)(0.0f);
    {
      const unsigned short* krow = &ksb[buf][(role * 16 + ln) * 256];
      #pragma unroll
      for (int ds = 0; ds < 8; ++ds) {
        short8 bk = *(const short8*)(krow + (((ds * 4 + quad) ^ swz) << 3));
        sf0 = __builtin_amdgcn_mfma_f32_16x16x32_bf16(aQ[0][ds], bk, sf0, 0, 0, 0);
        sf1 = __builtin_amdgcn_mfma_f32_16x16x32_bf16(aQ[1][ds], bk, sf1, 0, 0, 0);
      }
    }
    {
      unsigned short* pw = pb[buf];
      #pragma unroll
      for (int j = 0; j < 4; ++j) {
        float p0 = exp2f(sf0[j] * c2);
        float p1 = exp2f(sf1[j] * c2);
        lrow[0][j] += p0;
        lrow[1][j] += p1;
        const int r0 = qh * 32 + quad * 4 + j;          // strip 0
        const int r1 = r0 + 16;                          // strip 1
        pw[r0 * P_STRIDE + (((pwSig + (r0 >> 2)) & 7) << 3) + (ln & 7)] = f2bf(p0);
        pw[r1 * P_STRIDE + (((pwSig + (r1 >> 2)) & 7) << 3) + (ln & 7)] = f2bf(p1);
      }
    }

    // --- PV(t-1): d-quarter role*64..+63, both strips, all 64 keys ---
    if (t > 0) {
      const unsigned short* pr = pb[buf ^ 1];
      const unsigned short* kt = ktb[buf ^ 1];
      #pragma unroll
      for (int ks = 0; ks < 2; ++ks) {
        short8 ap[2], bv[4];
        #pragma unroll
        for (int s = 0; s < 2; ++s) {
          const int r = qh * 32 + s * 16 + ln;
          const int pos = (prSigBase + ks + (r >> 2)) & 7;
          ap[s] = *(const short8*)(&pr[r * P_STRIDE + (pos << 3)]);
        }
        const unsigned short* kb = kt + (ks * 4 + quad) * 2048 + (role * 64 + ln) * 8;
        #pragma unroll
        for (int dt = 0; dt < 4; ++dt) bv[dt] = *(const short8*)(kb + dt * 128);
        #pragma unroll
        for (int s = 0; s < 2; ++s)
          #pragma unroll
          for (int dt = 0; dt < 4; ++dt)
            o[s][dt] = __builtin_amdgcn_mfma_f32_16x16x32_bf16(ap[s], bv[dt], o[s][dt], 0, 0, 0);
      }
    }
  }

  __syncthreads();  // P(63), Kt(63) resident
  // --- PV(63) ---
  {
    const unsigned short* pr = pb[1];
    const unsigned short* kt = ktb[1];
    #pragma unroll
    for (int ks = 0; ks < 2; ++ks) {
      short8 ap[2], bv[4];
      #pragma unroll
      for (int s = 0; s < 2; ++s) {
        const int r = qh * 32 + s * 16 + ln;
        const int pos = (prSigBase + ks + (r >> 2)) & 7;
        ap[s] = *(const short8*)(&pr[r * P_STRIDE + (pos << 3)]);
      }
      const unsigned short* kb = kt + (ks * 4 + quad) * 2048 + (role * 64 + ln) * 8;
      #pragma unroll
      for (int dt = 0; dt < 4; ++dt) bv[dt] = *(const short8*)(kb + dt * 128);
      #pragma unroll
      for (int s = 0; s < 2; ++s)
        #pragma unroll
        for (int dt = 0; dt < 4; ++dt)
          o[s][dt] = __builtin_amdgcn_mfma_f32_16x16x32_bf16(ap[s], bv[dt], o[s][dt], 0, 0, 0);
    }
  }

  // --- merge l across the 4 roles, divide, store ---
  #pragma unroll
  for (int off = 1; off < 16; off <<= 1)
    #pragma unroll
    for (int s = 0; s < 2; ++s)
      #pragma unroll
      for (int j = 0; j < 4; ++j)
        lrow[s][j] += __shfl_xor(lrow[s][j], off, 64);
  if (ln == 0) {
    #pragma unroll
    for (int s = 0; s < 2; ++s)
      #pragma unroll
      for (int j = 0; j < 4; ++j)
        lbuf[qh * 32 + s * 16 + quad * 4 + j][role] = lrow[s][j];
  }
  __syncthreads();

  #pragma unroll
  for (int s = 0; s < 2; ++s) {
    float* outp = Out + (size_t)(b * NTOK + qblk * 64 + qh * 32 + s * 16) * DIM + role * 64;
    #pragma unroll
    for (int j = 0; j < 4; ++j) {
      const int row = s * 16 + quad * 4 + j;
      f32x4 lv = *(const f32x4*)lbuf[qh * 32 + row];
      const float rl = 1.0f / (lv[0] + lv[1] + lv[2] + lv[3]);
      #pragma unroll
      for (int dt = 0; dt < 4; ++dt)
        outp[(size_t)(quad * 4 + j) * DIM + dt * 16 + ln] = o[s][dt][j] * rl;
    }
  }
}

extern "C" void kernel_launch(void* const* d_in, const int* in_sizes, int n_in,
                              void* d_out, int out_size, void* d_ws, size_t ws_size,
                              hipStream_t stream) {
  const float* X = (const float*)d_in[0];       // x: fp32 [4,4096,256]
  float* Out = (float*)d_out;                   // fp32 [4,4096,256]
  unsigned short* Img = (unsigned short*)d_ws;  // 16 MB bf16 tile images
  (void)in_sizes; (void)n_in; (void)out_size; (void)ws_size;
  hipLaunchKernelGGL(prep_kernel, dim3(2048), dim3(256), 0, stream, X, Img);
  hipLaunchKernelGGL(fa_kernel, dim3(256), dim3(512), 0, stream, Img, Out);
}

// Round 8
// 173.465 us; speedup vs baseline: 1.4834x; 1.0026x over previous
//
#include <hip/hip_runtime.h>

typedef __attribute__((ext_vector_type(8))) short short8;
typedef __attribute__((ext_vector_type(4))) float f32x4;
typedef __attribute__((ext_vector_type(4))) unsigned int u32x4;

#define NTOK 4096
#define DIM  256
#define P_STRIDE 72        // P row stride elems (144 B); chunk kc at pos = kc ^ (2*((r>>3)&1))
#define TILE_ELEMS 32768   // ushort elems per 64KB tile image (Ks 16384 | Kt 16384)

__device__ __forceinline__ unsigned pack2bf(float a, float b) {
  unsigned ua = __builtin_bit_cast(unsigned, a) + 0x8000u;
  unsigned ub = __builtin_bit_cast(unsigned, b) + 0x8000u;
  return __builtin_amdgcn_perm(ub, ua, 0x07060302u); // low=bf16(a), high=bf16(b)
}

// ---- prologue: per-tile bf16 images (unchanged) --------------------------
// Img[b][t] = [ Ks: 64 rows x 32 chunks(16B), chunk c at (c ^ (r&7))
//             | Kt: 8 kb-blocks x 256 d x 8 tokens ]
__global__ __launch_bounds__(256, 4)
void prep_kernel(const float* __restrict__ X, unsigned short* __restrict__ Img) {
  const int b    = blockIdx.x & 3;
  const int sub  = blockIdx.x >> 2;   // 0..511
  const int t    = sub >> 3;
  const int part = sub & 7;
  const int tid  = threadIdx.x;
  const float* src = X + ((size_t)b * NTOK + t * 64) * DIM;
  unsigned short* dst = Img + ((size_t)(b * 64 + t)) * TILE_ELEMS;
  {
    int r = part * 8 + (tid >> 5);
    int c = tid & 31;
    const float* s = src + r * DIM + c * 8;
    f32x4 f0 = *(const f32x4*)s;
    f32x4 f1 = *(const f32x4*)(s + 4);
    union { unsigned u[4]; u32x4 v; } p;
    p.u[0] = pack2bf(f0[0], f0[1]);
    p.u[1] = pack2bf(f0[2], f0[3]);
    p.u[2] = pack2bf(f1[0], f1[1]);
    p.u[3] = pack2bf(f1[2], f1[3]);
    *(u32x4*)(dst + r * 256 + ((c ^ (r & 7)) << 3)) = p.v;
  }
  {
    const int d = tid;
    float f[8];
    #pragma unroll
    for (int i = 0; i < 8; ++i) f[i] = src[(part * 8 + i) * DIM + d];
    union { unsigned u[4]; u32x4 v; } p;
    p.u[0] = pack2bf(f[0], f[1]);
    p.u[1] = pack2bf(f[2], f[3]);
    p.u[2] = pack2bf(f[4], f[5]);
    p.u[3] = pack2bf(f[6], f[7]);
    *(u32x4*)(dst + 16384 + part * 2048 + d * 8) = p.v;
  }
}

// PV: O[s][dt] += P(strips of qh) x V(d-quarter role); pos = kc ^ (2*(ln>>3))
__device__ __forceinline__ void pv_step(const unsigned short* __restrict__ pr,
                                        const unsigned short* __restrict__ kt,
                                        f32x4 (&o)[2][4],
                                        int qh, int role, int quad, int ln) {
  #pragma unroll
  for (int ks = 0; ks < 2; ++ks) {
    const int pos = (ks * 4 + quad) ^ ((ln >> 3) << 1);
    short8 ap[2], bv[4];
    #pragma unroll
    for (int s = 0; s < 2; ++s) {
      const int r = qh * 32 + s * 16 + ln;
      ap[s] = *(const short8*)(&pr[r * P_STRIDE + (pos << 3)]);
    }
    const unsigned short* kb = kt + (ks * 4 + quad) * 2048 + (role * 64 + ln) * 8;
    #pragma unroll
    for (int dt = 0; dt < 4; ++dt) bv[dt] = *(const short8*)(kb + dt * 128);
    #pragma unroll
    for (int s = 0; s < 2; ++s)
      #pragma unroll
      for (int dt = 0; dt < 4; ++dt)
        o[s][dt] = __builtin_amdgcn_mfma_f32_16x16x32_bf16(ap[s], bv[dt], o[s][dt], 0, 0, 0);
  }
}

// ---- flash-attention: uniform waves, 1 barrier/iter, P dbuf --------------
__global__ __launch_bounds__(512, 1)
void fa_kernel(const unsigned short* __restrict__ Img, float* __restrict__ Out) {
  __shared__ __align__(16) unsigned short ksb[2][16384];        // 64 KB
  __shared__ __align__(16) unsigned short ktb[2][16384];        // 64 KB
  __shared__ __align__(16) unsigned short pb[2][64 * P_STRIDE]; // 18 KB
  __shared__ float lbuf[64][4];                                 // 1 KB

  const int tid  = threadIdx.x;
  const int b    = blockIdx.x & 3;
  const int qblk = blockIdx.x >> 2;
  const int wave = tid >> 6;
  const int lane = tid & 63;
  const int ln   = lane & 15;
  const int quad = lane >> 4;
  const int swz  = ln & 7;
  const int qh   = wave & 1;
  const int role = wave >> 1;

  const unsigned short* imgb  = Img + (size_t)b * 64 * TILE_ELEMS;
  const char*           imgbc = (const char*)imgb;

  short8 aQ[2][8];
  #pragma unroll
  for (int s = 0; s < 2; ++s) {
    const unsigned short* qrow =
        imgb + (size_t)qblk * TILE_ELEMS + (qh * 32 + s * 16 + ln) * 256;
    #pragma unroll
    for (int ds = 0; ds < 8; ++ds)
      aQ[s][ds] = *(const short8*)(qrow + (((ds * 4 + quad) ^ swz) << 3));
  }

  f32x4 o[2][4];
  #pragma unroll
  for (int s = 0; s < 2; ++s)
    #pragma unroll
    for (int dt = 0; dt < 4; ++dt) o[s][dt] = (f32x4)(0.0f);
  float lrow[2][4] = {{0.f,0.f,0.f,0.f},{0.f,0.f,0.f,0.f}};

  const float c2 = 0.0901684400f;  // log2(e)/sqrt(256)

  // P write constants: kc = role*2 + (ln>>3); pos = kc ^ (2*(quad>>1))
  const int pwPos = ((role * 2 + (ln >> 3)) ^ ((quad >> 1) << 1)) << 3;
  const int pwCol = ln & 7;  // even lanes write dword covering cols (pwCol, pwCol+1)

  const bool dmaKs = wave < 4;
  const int  dmaQ  = wave & 3;
  const char* gK = imgbc + (size_t)dmaQ * 8192 + (size_t)lane * 16;

  if (dmaKs) {
    #pragma unroll
    for (int i = 0; i < 8; ++i)
      __builtin_amdgcn_global_load_lds(
          (const __attribute__((address_space(1))) unsigned*)(gK + i * 1024),
          (__attribute__((address_space(3))) unsigned*)(&ksb[0][dmaQ * 4096 + i * 512]),
          16, 0, 0);
  }

  for (int t = 0; t < 64; ++t) {
    __syncthreads();  // drains last iter's DMA; P(t-1)/Ks(t)/Kt(t-1) ready
    const int buf = t & 1;

    if (dmaKs) {
      if (t < 63) {
        const char* g = gK + (size_t)(t + 1) * 65536;
        unsigned short* l = &ksb[buf ^ 1][dmaQ * 4096];
        #pragma unroll
        for (int i = 0; i < 8; ++i)
          __builtin_amdgcn_global_load_lds(
              (const __attribute__((address_space(1))) unsigned*)(g + i * 1024),
              (__attribute__((address_space(3))) unsigned*)(l + i * 512),
              16, 0, 0);
      }
    } else {
      const char* g = gK + (size_t)t * 65536 + 32768;
      unsigned short* l = &ktb[buf][dmaQ * 4096];
      #pragma unroll
      for (int i = 0; i < 8; ++i)
        __builtin_amdgcn_global_load_lds(
            (const __attribute__((address_space(1))) unsigned*)(g + i * 1024),
            (__attribute__((address_space(3))) unsigned*)(l + i * 512),
            16, 0, 0);
    }

    // --- QK(t): keys role*16..+15, both strips ---
    f32x4 sf0 = (f32x4)(0.0f), sf1 = (f32x4)(0.0f);
    {
      const unsigned short* krow = &ksb[buf][(role * 16 + ln) * 256];
      #pragma unroll
      for (int ds = 0; ds < 8; ++ds) {
        short8 bk = *(const short8*)(krow + (((ds * 4 + quad) ^ swz) << 3));
        sf0 = __builtin_amdgcn_mfma_f32_16x16x32_bf16(aQ[0][ds], bk, sf0, 0, 0, 0);
        sf1 = __builtin_amdgcn_mfma_f32_16x16x32_bf16(aQ[1][ds], bk, sf1, 0, 0, 0);
      }
    }
    // --- softmax numerators; packed conflict-free P store ---
    {
      unsigned short* pw = pb[buf];
      #pragma unroll
      for (int j = 0; j < 4; ++j) {
        float p0 = __builtin_amdgcn_exp2f(sf0[j] * c2);
        float p1 = __builtin_amdgcn_exp2f(sf1[j] * c2);
        lrow[0][j] += p0;
        lrow[1][j] += p1;
        unsigned q0 = __builtin_bit_cast(unsigned, p0);
        unsigned q1 = __builtin_bit_cast(unsigned, p1);
        // partner (lane^1) via DPP quad_perm [1,0,3,2] = 0xB1 (pure VALU)
        unsigned n0 = (unsigned)__builtin_amdgcn_mov_dpp((int)q0, 0xB1, 0xF, 0xF, true);
        unsigned n1 = (unsigned)__builtin_amdgcn_mov_dpp((int)q1, 0xB1, 0xF, 0xF, true);
        if ((ln & 1) == 0) {
          const int r0 = qh * 32 + quad * 4 + j;
          unsigned d0 = pack2bf(__builtin_bit_cast(float, q0), __builtin_bit_cast(float, n0));
          unsigned d1 = pack2bf(__builtin_bit_cast(float, q1), __builtin_bit_cast(float, n1));
          *(unsigned*)(&pw[r0 * P_STRIDE + pwPos + pwCol]) = d0;
          *(unsigned*)(&pw[(r0 + 16) * P_STRIDE + pwPos + pwCol]) = d1;
        }
      }
    }

    // --- PV(t-1): d-quarter role*64..+63, both strips, all 64 keys ---
    if (t > 0)
      pv_step(pb[buf ^ 1], ktb[buf ^ 1], o, qh, role, quad, ln);
  }

  __syncthreads();  // P(63), Kt(63) resident
  pv_step(pb[1], ktb[1], o, qh, role, quad, ln);  // final tile

  // --- merge l across the 4 roles, divide, store ---
  #pragma unroll
  for (int off = 1; off < 16; off <<= 1)
    #pragma unroll
    for (int s = 0; s < 2; ++s)
      #pragma unroll
      for (int j = 0; j < 4; ++j)
        lrow[s][j] += __shfl_xor(lrow[s][j], off, 64);
  if (ln == 0) {
    #pragma unroll
    for (int s = 0; s < 2; ++s)
      #pragma unroll
      for (int j = 0; j < 4; ++j)
        lbuf[qh * 32 + s * 16 + quad * 4 + j][role] = lrow[s][j];
  }
  __syncthreads();

  #pragma unroll
  for (int s = 0; s < 2; ++s) {
    float* outp = Out + (size_t)(b * NTOK + qblk * 64 + qh * 32 + s * 16) * DIM + role * 64;
    #pragma unroll
    for (int j = 0; j < 4; ++j) {
      const int row = s * 16 + quad * 4 + j;
      f32x4 lv = *(const f32x4*)lbuf[qh * 32 + row];
      const float rl = 1.0f / (lv[0] + lv[1] + lv[2] + lv[3]);
      #pragma unroll
      for (int dt = 0; dt < 4; ++dt)
        outp[(size_t)(quad * 4 + j) * DIM + dt * 16 + ln] = o[s][dt][j] * rl;
    }
  }
}

extern "C" void kernel_launch(void* const* d_in, const int* in_sizes, int n_in,
                              void* d_out, int out_size, void* d_ws, size_t ws_size,
                              hipStream_t stream) {
  const float* X = (const float*)d_in[0];       // x: fp32 [4,4096,256]
  float* Out = (float*)d_out;                   // fp32 [4,4096,256]
  unsigned short* Img = (unsigned short*)d_ws;  // 16 MB bf16 tile images
  (void)in_sizes; (void)n_in; (void)out_size; (void)ws_size;
  hipLaunchKernelGGL(prep_kernel, dim3(2048), dim3(256), 0, stream, X, Img);
  hipLaunchKernelGGL(fa_kernel, dim3(256), dim3(512), 0, stream, Img, Out);
}